// Round 1
// baseline (277.137 us; speedup 1.0000x reference)
//
#include <hip/hip_runtime.h>
#include <cstdint>

#define N_NODES 50000
#define TILE 32
#define NBLK ((N_NODES + TILE - 1) / TILE)  // 1563

// fragment / accumulator vector types (gfx950 mfma bf16 builtins take v8 bf16)
typedef __bf16 bf16x8 __attribute__((ext_vector_type(8)));
typedef unsigned short ushort8_t __attribute__((ext_vector_type(8)));
typedef float f32x4 __attribute__((ext_vector_type(4)));

__device__ __forceinline__ unsigned short f2bf(float x) {
  union { float f; uint32_t u; } v; v.f = x;
  uint32_t r = v.u + 0x7FFFu + ((v.u >> 16) & 1u);  // RNE
  return (unsigned short)(r >> 16);
}

__device__ __forceinline__ float fast_silu(float x) {
  return x / (1.0f + __expf(-x));
}

// ---------------------------------------------------------------------------
// Prologue: shuffle all 8 weight matrices (fp32 [f][g], 128x128) into
// B-fragment-ordered bf16 atoms in d_ws.
// Atom (c in 0..7 coltile, kt in 0..3 kstep, lane in 0..63) holds 8 bf16:
//   W[k0+j][g],  g = (lane&15)+16c,  k0 = 32kt + (lane>>4)*8,  j=0..7
// so the main kernel's B-frag load is simply ds_read_b128 at atom*16.
// ---------------------------------------------------------------------------
__global__ __launch_bounds__(256) void prep_weights(
    const float* __restrict__ Wq1, const float* __restrict__ Wq2,
    const float* __restrict__ WT1, const float* __restrict__ WT2,
    const float* __restrict__ WT3, const float* __restrict__ Ws1,
    const float* __restrict__ Ws2, const float* __restrict__ Wv,
    unsigned short* __restrict__ ws) {
  int tid = blockIdx.x * 256 + threadIdx.x;
  int w = tid >> 11;          // which weight (0..7), 2048 atoms each
  int rest = tid & 2047;      // atom index = (c*4+kt)*64 + lane
  int c = rest >> 8;
  int kt = (rest >> 6) & 3;
  int lane = rest & 63;
  int g = (lane & 15) + 16 * c;
  int k0 = kt * 32 + (lane >> 4) * 8;
  const float* srcs[8] = {Wq1, Wq2, WT1, WT2, WT3, Ws1, Ws2, Wv};
  const float* src = srcs[w];
  union { unsigned short u[8]; uint4 v; } o;
#pragma unroll
  for (int j = 0; j < 8; ++j) o.u[j] = f2bf(src[(k0 + j) * 128 + g]);
  *(uint4*)(ws + (size_t)w * 16384 + (size_t)rest * 8) = o.v;
}

// ---------------------------------------------------------------------------
// GEMM: Y[32 x 128] = A[32 x 128] @ W[128 x 128] on one block (4 waves).
// Wave owns rows 0..31 x cols [32*wv, 32*wv+32): 2x2 tiles of 16x16.
// sA: bf16, row stride 136 (pad +8 breaks b128 bank conflicts).
// sWp: frag-ordered atoms (see prep_weights).
// ---------------------------------------------------------------------------
__device__ __forceinline__ void gemm16(const unsigned short* sA,
                                       const unsigned short* sWp,
                                       int lane, int cb, f32x4 acc[2][2]) {
  const int m = lane & 15, q = lane >> 4;
  const f32x4 vzero = {0.f, 0.f, 0.f, 0.f};
#pragma unroll
  for (int rt = 0; rt < 2; ++rt)
#pragma unroll
    for (int cc = 0; cc < 2; ++cc) acc[rt][cc] = vzero;
#pragma unroll
  for (int kt = 0; kt < 4; ++kt) {
    const int k0 = q * 8 + kt * 32;
    bf16x8 a0 = __builtin_bit_cast(bf16x8, *(const ushort8_t*)(sA + m * 136 + k0));
    bf16x8 a1 = __builtin_bit_cast(bf16x8, *(const ushort8_t*)(sA + (m + 16) * 136 + k0));
#pragma unroll
    for (int cc = 0; cc < 2; ++cc) {
      bf16x8 b = __builtin_bit_cast(
          bf16x8, *(const ushort8_t*)(sWp + (((cb + cc) * 4 + kt) * 64 + lane) * 8));
      acc[0][cc] = __builtin_amdgcn_mfma_f32_16x16x32_bf16(a0, b, acc[0][cc], 0, 0, 0);
      acc[1][cc] = __builtin_amdgcn_mfma_f32_16x16x32_bf16(a1, b, acc[1][cc], 0, 0, 0);
    }
  }
}

// ---------------------------------------------------------------------------
// Fused main kernel: one block = 32 nodes, full pipeline.
// Stage order: H=silu(feat@Wq1+b) -> M0 -> M1(3ch) -> M3(3ch) -> M2(3ch)
//  -> flush mv/ms -> dense_s -> mv@Wv.
// ---------------------------------------------------------------------------
__global__ __launch_bounds__(256, 2) void multipole_main(
    const float* __restrict__ feat, const float* __restrict__ mu,
    const float* __restrict__ T0g, const float* __restrict__ T1g,
    const float* __restrict__ T2g, const float* __restrict__ T3g,
    const float* __restrict__ bq1, const float* __restrict__ bq2,
    const float* __restrict__ bs1, const float* __restrict__ bs2,
    const unsigned short* __restrict__ ws, float* __restrict__ out) {
  __shared__ unsigned short sW[16384];          // 32 KB: current weight (frag-ordered)
  __shared__ unsigned short sXmain[TILE * 136]; // feat -> H -> ms -> G
  __shared__ unsigned short sXmu[3][TILE * 136];// mu channels, later mv channels
  __shared__ float sT[TILE][49];                // per-node T0/T1/T2raw/sym coeffs

  const int t = threadIdx.x;
  const int lane = t & 63, wv = t >> 6;
  const int m = lane & 15, q = lane >> 4;
  const int cb = wv * 2;  // wave's col-tile base (cols [cb*16, cb*16+32))
  const int nodeBase = blockIdx.x * TILE;

  auto stage_w = [&](int slot) {
    const uint4* src = (const uint4*)(ws + (size_t)slot * 16384);
    uint4* dst = (uint4*)sW;
#pragma unroll
    for (int i = 0; i < 8; ++i) dst[t + i * 256] = src[t + i * 256];
  };

  // ---- per-node T staging + symmetrization (threads 0..31) ----
  if (t < TILE) {
    int n = nodeBase + t;
    bool val = n < N_NODES;
    float t0 = val ? T0g[n] : 0.f;
    float t1[3], t2[9], t3[27];
#pragma unroll
    for (int i = 0; i < 3; ++i) t1[i] = val ? T1g[n * 3 + i] : 0.f;
#pragma unroll
    for (int i = 0; i < 9; ++i) t2[i] = val ? T2g[n * 9 + i] : 0.f;
#pragma unroll
    for (int i = 0; i < 27; ++i) t3[i] = val ? T3g[n * 27 + i] : 0.f;
    float* Tr = sT[t];
    Tr[0] = t0;
    Tr[1] = t1[0]; Tr[2] = t1[1]; Tr[3] = t1[2];
#pragma unroll
    for (int i = 0; i < 9; ++i) Tr[4 + i] = t2[i];        // raw T2[i][j]
    // q2: pairs (00,01,02,11,12,22) for sum_ij T2ij vi vj
    Tr[13] = t2[0]; Tr[14] = t2[1] + t2[3]; Tr[15] = t2[2] + t2[6];
    Tr[16] = t2[4]; Tr[17] = t2[5] + t2[7]; Tr[18] = t2[8];
    // c3: multisets (000,001,002,011,012,022,111,112,122,222)
    Tr[19] = t3[0];
    Tr[20] = t3[1] + t3[3] + t3[9];
    Tr[21] = t3[2] + t3[6] + t3[18];
    Tr[22] = t3[4] + t3[10] + t3[12];
    Tr[23] = t3[5] + t3[7] + t3[11] + t3[15] + t3[19] + t3[21];
    Tr[24] = t3[8] + t3[20] + t3[24];
    Tr[25] = t3[13];
    Tr[26] = t3[14] + t3[16] + t3[22];
    Tr[27] = t3[17] + t3[23] + t3[25];
    Tr[28] = t3[26];
    // d3[i][pair]: sum_jk T3[i][j][k] vj vk, pairs (00,01,02,11,12,22)
#pragma unroll
    for (int i = 0; i < 3; ++i) {
      const float* b = t3 + 9 * i;
      float* d = Tr + 29 + 6 * i;
      d[0] = b[0]; d[1] = b[1] + b[3]; d[2] = b[2] + b[6];
      d[3] = b[4]; d[4] = b[5] + b[7]; d[5] = b[8];
    }
  }

  // ---- feat tile -> sXmain (bf16) ----
  {
    int node = t >> 3, f0 = (t & 7) * 16;
    int gn = nodeBase + node;
    union { unsigned short u[16]; uint4 v[2]; } buf;
    if (gn < N_NODES) {
      const float* p = feat + (size_t)gn * 128 + f0;
#pragma unroll
      for (int i = 0; i < 16; ++i) buf.u[i] = f2bf(p[i]);
    } else {
#pragma unroll
      for (int i = 0; i < 16; ++i) buf.u[i] = 0;
    }
    uint4* dst = (uint4*)&sXmain[node * 136 + f0];
    dst[0] = buf.v[0]; dst[1] = buf.v[1];
  }
  stage_w(0);  // Wq1
  __syncthreads();

  f32x4 A1[2][2], A2[2][2], A3[2][2];
  float msv[2][2][4];
  float mvv[3][2][2][4];

  // ---- S1: H = silu(feat@Wq1 + bq1) ----
  gemm16(sXmain, sW, lane, cb, A1);
  float b0 = bq1[cb * 16 + m], b1 = bq1[cb * 16 + 16 + m];
  __syncthreads();
#pragma unroll
  for (int rt = 0; rt < 2; ++rt)
#pragma unroll
    for (int ri = 0; ri < 4; ++ri) {
      int lrow = rt * 16 + q * 4 + ri;
#pragma unroll
      for (int cc = 0; cc < 2; ++cc) {
        float h = fast_silu(A1[rt][cc][ri] + (cc ? b1 : b0));
        sXmain[lrow * 136 + (cb + cc) * 16 + m] = f2bf(h);
      }
    }
  stage_w(1);  // Wq2
  __syncthreads();

  // ---- S2: M0 = H@Wq2 + bq2 ; ms = T0*M0 ; mv_i = T1_i*M0 ----
  gemm16(sXmain, sW, lane, cb, A1);
  {
    float bb0 = bq2[cb * 16 + m], bb1 = bq2[cb * 16 + 16 + m];
#pragma unroll
    for (int rt = 0; rt < 2; ++rt)
#pragma unroll
      for (int ri = 0; ri < 4; ++ri) {
        const float* Tr = sT[rt * 16 + q * 4 + ri];
        float t0 = Tr[0], ta = Tr[1], tb = Tr[2], tc = Tr[3];
#pragma unroll
        for (int cc = 0; cc < 2; ++cc) {
          float m0 = A1[rt][cc][ri] + (cc ? bb1 : bb0);
          msv[rt][cc][ri] = t0 * m0;
          mvv[0][rt][cc][ri] = ta * m0;
          mvv[1][rt][cc][ri] = tb * m0;
          mvv[2][rt][cc][ri] = tc * m0;
        }
      }
  }
  __syncthreads();

  // ---- mu tile -> sXmu[3] (bf16, all channels) + WT1 ----
  {
    int node = t >> 3, f0 = (t & 7) * 16;
    int gn = nodeBase + node;
    union { unsigned short u[16]; uint4 v[2]; } b3[3];
    if (gn < N_NODES) {
      const float* p = mu + ((size_t)gn * 128 + f0) * 3;
#pragma unroll
      for (int i = 0; i < 16; ++i) {
        b3[0].u[i] = f2bf(p[i * 3 + 0]);
        b3[1].u[i] = f2bf(p[i * 3 + 1]);
        b3[2].u[i] = f2bf(p[i * 3 + 2]);
      }
    } else {
#pragma unroll
      for (int ch = 0; ch < 3; ++ch)
#pragma unroll
        for (int i = 0; i < 16; ++i) b3[ch].u[i] = 0;
    }
#pragma unroll
    for (int ch = 0; ch < 3; ++ch) {
      uint4* dst = (uint4*)&sXmu[ch][node * 136 + f0];
      dst[0] = b3[ch].v[0]; dst[1] = b3[ch].v[1];
    }
  }
  stage_w(2);  // WT1
  __syncthreads();

  // ---- M1 channels: ms += T1[c]*M1c ; mv_i += T2[i][c]*M1c ----
#pragma unroll
  for (int ch = 0; ch < 3; ++ch) {
    gemm16(sXmu[ch], sW, lane, cb, A1);
#pragma unroll
    for (int rt = 0; rt < 2; ++rt)
#pragma unroll
      for (int ri = 0; ri < 4; ++ri) {
        const float* Tr = sT[rt * 16 + q * 4 + ri];
        float t1c = Tr[1 + ch];
        float u0 = Tr[4 + 0 + ch], u1 = Tr[4 + 3 + ch], u2 = Tr[4 + 6 + ch];
#pragma unroll
        for (int cc = 0; cc < 2; ++cc) {
          float v = A1[rt][cc][ri];
          msv[rt][cc][ri] += t1c * v;
          mvv[0][rt][cc][ri] += u0 * v;
          mvv[1][rt][cc][ri] += u1 * v;
          mvv[2][rt][cc][ri] += u2 * v;
        }
      }
  }
  __syncthreads();
  stage_w(4);  // WT3
  __syncthreads();

  // ---- M3 channels then cubic: ms += sum c3[ijk] u_i u_j u_k ----
  gemm16(sXmu[0], sW, lane, cb, A1);
  gemm16(sXmu[1], sW, lane, cb, A2);
  gemm16(sXmu[2], sW, lane, cb, A3);
#pragma unroll
  for (int rt = 0; rt < 2; ++rt)
#pragma unroll
    for (int ri = 0; ri < 4; ++ri) {
      const float* Cp = sT[rt * 16 + q * 4 + ri] + 19;
      float c0 = Cp[0], c1 = Cp[1], c2 = Cp[2], c3 = Cp[3], c4 = Cp[4];
      float c5 = Cp[5], c6 = Cp[6], c7 = Cp[7], c8 = Cp[8], c9 = Cp[9];
#pragma unroll
      for (int cc = 0; cc < 2; ++cc) {
        float u0 = A1[rt][cc][ri], u1 = A2[rt][cc][ri], u2 = A3[rt][cc][ri];
        float Q0 = u0 * u0, Q1 = u0 * u1, Q2 = u0 * u2;
        float Q3 = u1 * u1, Q4 = u1 * u2, Q5 = u2 * u2;
        msv[rt][cc][ri] += c0 * (Q0 * u0) + c1 * (Q0 * u1) + c2 * (Q0 * u2) +
                           c3 * (Q1 * u1) + c4 * (Q1 * u2) + c5 * (Q2 * u2) +
                           c6 * (Q3 * u1) + c7 * (Q3 * u2) + c8 * (Q4 * u2) +
                           c9 * (Q5 * u2);
      }
    }
  __syncthreads();
  stage_w(3);  // WT2
  __syncthreads();

  // ---- M2 channels then quadratic: ms += q2:PP ; mv_i += d3_i:PP ----
  gemm16(sXmu[0], sW, lane, cb, A1);
  gemm16(sXmu[1], sW, lane, cb, A2);
  gemm16(sXmu[2], sW, lane, cb, A3);
#pragma unroll
  for (int rt = 0; rt < 2; ++rt)
#pragma unroll
    for (int ri = 0; ri < 4; ++ri) {
      const float* Tr = sT[rt * 16 + q * 4 + ri];
      const float* q2 = Tr + 13;
      const float* d3 = Tr + 29;
      float q20 = q2[0], q21 = q2[1], q22 = q2[2], q23 = q2[3], q24 = q2[4], q25 = q2[5];
#pragma unroll
      for (int cc = 0; cc < 2; ++cc) {
        float v0 = A1[rt][cc][ri], v1 = A2[rt][cc][ri], v2 = A3[rt][cc][ri];
        float P0 = v0 * v0, P1 = v0 * v1, P2 = v0 * v2;
        float P3 = v1 * v1, P4 = v1 * v2, P5 = v2 * v2;
        msv[rt][cc][ri] += q20 * P0 + q21 * P1 + q22 * P2 + q23 * P3 + q24 * P4 + q25 * P5;
        mvv[0][rt][cc][ri] += d3[0] * P0 + d3[1] * P1 + d3[2] * P2 + d3[3] * P3 + d3[4] * P4 + d3[5] * P5;
        mvv[1][rt][cc][ri] += d3[6] * P0 + d3[7] * P1 + d3[8] * P2 + d3[9] * P3 + d3[10] * P4 + d3[11] * P5;
        mvv[2][rt][cc][ri] += d3[12] * P0 + d3[13] * P1 + d3[14] * P2 + d3[15] * P3 + d3[16] * P4 + d3[17] * P5;
      }
    }
  __syncthreads();

  // ---- flush ms -> sXmain, mv -> sXmu (bf16, A-operand layout) ----
#pragma unroll
  for (int rt = 0; rt < 2; ++rt)
#pragma unroll
    for (int ri = 0; ri < 4; ++ri) {
      int lrow = rt * 16 + q * 4 + ri;
#pragma unroll
      for (int cc = 0; cc < 2; ++cc) {
        int col = (cb + cc) * 16 + m;
        sXmain[lrow * 136 + col] = f2bf(msv[rt][cc][ri]);
        sXmu[0][lrow * 136 + col] = f2bf(mvv[0][rt][cc][ri]);
        sXmu[1][lrow * 136 + col] = f2bf(mvv[1][rt][cc][ri]);
        sXmu[2][lrow * 136 + col] = f2bf(mvv[2][rt][cc][ri]);
      }
    }
  stage_w(5);  // Ws1
  __syncthreads();

  // ---- S12: G = silu(ms@Ws1 + bs1) ----
  gemm16(sXmain, sW, lane, cb, A1);
  {
    float s0 = bs1[cb * 16 + m], s1 = bs1[cb * 16 + 16 + m];
    __syncthreads();
#pragma unroll
    for (int rt = 0; rt < 2; ++rt)
#pragma unroll
      for (int ri = 0; ri < 4; ++ri) {
        int lrow = rt * 16 + q * 4 + ri;
#pragma unroll
        for (int cc = 0; cc < 2; ++cc) {
          float g = fast_silu(A1[rt][cc][ri] + (cc ? s1 : s0));
          sXmain[lrow * 136 + (cb + cc) * 16 + m] = f2bf(g);
        }
      }
  }
  stage_w(6);  // Ws2
  __syncthreads();

  // ---- S13: ms_out = G@Ws2 + bs2 -> out[0 : N*128] ----
  gemm16(sXmain, sW, lane, cb, A1);
  {
    float s0 = bs2[cb * 16 + m], s1 = bs2[cb * 16 + 16 + m];
#pragma unroll
    for (int rt = 0; rt < 2; ++rt)
#pragma unroll
      for (int ri = 0; ri < 4; ++ri) {
        int grow = nodeBase + rt * 16 + q * 4 + ri;
        if (grow < N_NODES) {
#pragma unroll
          for (int cc = 0; cc < 2; ++cc) {
            int col = (cb + cc) * 16 + m;
            out[(size_t)grow * 128 + col] = A1[rt][cc][ri] + (cc ? s1 : s0);
          }
        }
      }
  }
  __syncthreads();
  stage_w(7);  // Wv
  __syncthreads();

  // ---- S14-16: mv_out[:, :, ch] = mv_ch @ Wv -> out[N*128 :], [N,A,3] ----
  float* out2 = out + (size_t)N_NODES * 128;
#pragma unroll
  for (int ch = 0; ch < 3; ++ch) {
    gemm16(sXmu[ch], sW, lane, cb, A1);
#pragma unroll
    for (int rt = 0; rt < 2; ++rt)
#pragma unroll
      for (int ri = 0; ri < 4; ++ri) {
        int grow = nodeBase + rt * 16 + q * 4 + ri;
        if (grow < N_NODES) {
#pragma unroll
          for (int cc = 0; cc < 2; ++cc) {
            int col = (cb + cc) * 16 + m;
            out2[((size_t)grow * 128 + col) * 3 + ch] = A1[rt][cc][ri];
          }
        }
      }
  }
}

extern "C" void kernel_launch(void* const* d_in, const int* in_sizes, int n_in,
                              void* d_out, int out_size, void* d_ws, size_t ws_size,
                              hipStream_t stream) {
  const float* feat = (const float*)d_in[0];
  const float* mu   = (const float*)d_in[1];
  const float* T0   = (const float*)d_in[2];
  const float* T1   = (const float*)d_in[3];
  const float* T2   = (const float*)d_in[4];
  const float* T3   = (const float*)d_in[5];
  const float* Wq1  = (const float*)d_in[6];
  const float* bq1  = (const float*)d_in[7];
  const float* Wq2  = (const float*)d_in[8];
  const float* bq2  = (const float*)d_in[9];
  const float* WT1  = (const float*)d_in[10];
  const float* WT2  = (const float*)d_in[11];
  const float* WT3  = (const float*)d_in[12];
  const float* Ws1  = (const float*)d_in[13];
  const float* bs1  = (const float*)d_in[14];
  const float* Ws2  = (const float*)d_in[15];
  const float* bs2  = (const float*)d_in[16];
  const float* Wv   = (const float*)d_in[17];
  unsigned short* ws = (unsigned short*)d_ws;  // needs 8*128*128*2 = 256 KB
  float* out = (float*)d_out;

  prep_weights<<<64, 256, 0, stream>>>(Wq1, Wq2, WT1, WT2, WT3, Ws1, Ws2, Wv, ws);
  multipole_main<<<NBLK, 256, 0, stream>>>(feat, mu, T0, T1, T2, T3,
                                           bq1, bq2, bs1, bs2, ws, out);
}